// Round 8
// baseline (538.237 us; speedup 1.0000x reference)
//
#include <hip/hip_runtime.h>
#include <hip/hip_bf16.h>
#include <stdint.h>

#define N_NODES 50000
#define N_EDGES 500000
#define NODE_IN 128
#define EDGE_IN 64
#define HID 128
#define K_H1 384   // 3*HID
#define N_H1 512   // 4*HID
#define N_H2 256   // 2*HID

#define EPB 64     // edges per block -> 2 independent blocks/CU

typedef short s8v __attribute__((ext_vector_type(8)));    // 8 x bf16 bits (4 VGPR)
typedef float f4v __attribute__((ext_vector_type(4)));    // 16x16 MFMA accumulator
typedef float f16v __attribute__((ext_vector_type(16)));  // 32x32 MFMA accumulator

// HW packed fp32->bf16 (v_cvt_pk_bf16_f32): low 16 bits = a, high = b
__device__ __forceinline__ unsigned int pk_bf16(float a, float b) {
    union { __hip_bfloat162 h; unsigned int u; } c;
    c.h = __float22bfloat162_rn(float2{a, b});
    return c.u;
}

// Load 8 consecutive fp32 from global, convert to a bf16 fragment (16x16x32 map).
__device__ __forceinline__ s8v load_a_f32(const float* __restrict__ base, int row, int ld, int koff) {
    const float4* p = (const float4*)(base + row * ld + koff);
    float4 x0 = p[0];
    float4 x1 = p[1];
    union { s8v v; unsigned int u[4]; } r;
    r.u[0] = pk_bf16(x0.x, x0.y);
    r.u[1] = pk_bf16(x0.z, x0.w);
    r.u[2] = pk_bf16(x1.x, x1.y);
    r.u[3] = pk_bf16(x1.z, x1.w);
    return r.v;
}

// 16x16x32 pack (Wn, We): dst[((kb*(N/16)+nt)*64+lane)*8+j] =
//   W[kb*32 + (lane>>4)*8 + j][nt*16 + (lane&15)]
__device__ __forceinline__ void pack_one(const float* __restrict__ src, unsigned short* __restrict__ dst,
                                         int idx, int N) {
    int j = idx & 7;
    int lane = (idx >> 3) & 63;
    int rest = idx >> 9;
    int NT = N >> 4;
    int nt = rest % NT;
    int kb = rest / NT;
    int n = nt * 16 + (lane & 15);
    int k = kb * 32 + ((lane >> 4) << 3) + j;
    union { __hip_bfloat16 h; unsigned short s; } c;
    c.h = __float2bfloat16(src[k * N + n]);
    dst[idx] = c.s;
}

// 32x32x16 pack (W1, W2): dst[((ks*(N/32)+nt)*64+lane)*8+j] =
//   W[ks*16 + (lane>>5)*8 + j][nt*32 + (lane&31)]
// A-frag map for mfma_32x32x16: lane holds A[row=l&31][k=(l>>5)*8+j].
__device__ __forceinline__ void pack_one32(const float* __restrict__ src, unsigned short* __restrict__ dst,
                                           int idx, int N) {
    int j = idx & 7;
    int lane = (idx >> 3) & 63;
    int rest = idx >> 9;
    int NT = N >> 5;
    int nt = rest % NT;
    int ks = rest / NT;
    int n = nt * 32 + (lane & 31);
    int k = ks * 16 + ((lane >> 5) << 3) + j;
    union { __hip_bfloat16 h; unsigned short s; } c;
    c.h = __float2bfloat16(src[k * N + n]);
    dst[idx] = c.s;
}

#define WN_ELEMS (NODE_IN * HID)          // 16384
#define WE_ELEMS (EDGE_IN * HID)          // 8192
#define W1_ELEMS (K_H1 * N_H1)            // 196608
#define W2_ELEMS (N_H1 * N_H2)            // 131072
#define PACK_TOTAL (WN_ELEMS + WE_ELEMS + W1_ELEMS + W2_ELEMS)

__global__ void pack_all(const float* __restrict__ Wn, const float* __restrict__ We,
                         const float* __restrict__ W1, const float* __restrict__ W2,
                         unsigned short* __restrict__ Wnp, unsigned short* __restrict__ Wep,
                         unsigned short* __restrict__ W1p, unsigned short* __restrict__ W2p) {
    int idx = blockIdx.x * blockDim.x + threadIdx.x;
    if (idx >= PACK_TOTAL) return;
    if (idx < WN_ELEMS) { pack_one(Wn, Wnp, idx, HID); return; }
    idx -= WN_ELEMS;
    if (idx < WE_ELEMS) { pack_one(We, Wep, idx, HID); return; }
    idx -= WE_ELEMS;
    if (idx < W1_ELEMS) { pack_one32(W1, W1p, idx, N_H1); return; }
    idx -= W1_ELEMS;
    pack_one32(W2, W2p, idx, N_H2);
}

// node_f^T formulation: D[m=hidcol][n=node] = Wn^T @ x^T (16x16x32, unchanged).
__global__ __launch_bounds__(256, 4) void node_feat_kernel(
    const float* __restrict__ x, const unsigned short* __restrict__ Wnp,
    const float* __restrict__ bn, unsigned short* __restrict__ node_f)
{
    int tid = threadIdx.x;
    int wave = tid >> 6, lane = tid & 63;
    int lm = lane & 15, quad = lane >> 4;
    int row0 = blockIdx.x * 64;
    int node = row0 + wave * 16 + lm;
    int nodec = node < N_NODES ? node : N_NODES - 1;

    f4v zero = {0.f, 0.f, 0.f, 0.f};
    f4v acc[8];
    #pragma unroll
    for (int mt = 0; mt < 8; ++mt) acc[mt] = zero;

    for (int kb = 0; kb < 4; ++kb) {
        s8v b = load_a_f32(x, nodec, NODE_IN, kb * 32 + quad * 8);
        #pragma unroll
        for (int mt = 0; mt < 8; ++mt) {
            s8v a = *(const s8v*)(Wnp + (((kb * 8 + mt) * 64 + lane) << 3));
            acc[mt] = __builtin_amdgcn_mfma_f32_16x16x32_bf16(a, b, acc[mt], 0, 0, 0);
        }
    }

    if (node < N_NODES) {
        #pragma unroll
        for (int mt = 0; mt < 8; ++mt) {
            float4 bv = *(const float4*)(bn + mt * 16 + quad * 4);
            uint2 pk;
            pk.x = pk_bf16(fmaxf(acc[mt][0] + bv.x, 0.f), fmaxf(acc[mt][1] + bv.y, 0.f));
            pk.y = pk_bf16(fmaxf(acc[mt][2] + bv.z, 0.f), fmaxf(acc[mt][3] + bv.w, 0.f));
            *(uint2*)(node_f + node * HID + mt * 16 + quad * 4) = pk;
        }
    }
}

// Fused per-edge pipeline. block: 512 threads (8 waves), 64 edges, 2 blocks/CU.
//
// ROUND-7/8: phases 2+3 use mfma_f32_32x32x16_bf16. Why: (a) +17% matrix
// ceiling (2382 vs 2075 TF) — r6's MfmaUtil 48% equals the 16x16 pipe floor;
// (b) half the MFMA issue count; (c) per K-step a M64xN64 wave tile needs
// only 2 A + 2 B frags, so a FULL even/odd double-buffer of both operands
// fits the 128-reg budget (acc 64 AGPR + 32 frag regs), which 16x16 could
// not (rounds 0/1 spilled). Counted vmcnt/lgkmcnt waits, rule-18 fenced.
// C/D map (guide, m101-verified): col=lane&31, row=(r&3)+8*(r>>2)+4*(lane>>5).
// Tripwires: WRITE_SIZE ~2 MB, absmax, VGPR <= ~84, bank-conflict counter.
#define CSTR 392   // comb row stride (shorts, 384 + 8 pad)
#define H1STR 520  // h1 row stride (shorts, 512 + 8 pad)

__global__ __launch_bounds__(512, 4) void fused_edge_kernel(
    const int* __restrict__ edge_index, const float* __restrict__ edge_attr,
    const unsigned short* __restrict__ node_f,
    const unsigned short* __restrict__ Wep, const float* __restrict__ be,
    const unsigned short* __restrict__ W1p, const float* __restrict__ b1,
    const unsigned short* __restrict__ W2p, const float* __restrict__ b2,
    const float* __restrict__ W3, const float* __restrict__ b3,
    float* __restrict__ out)
{
    // union buffer: phase1/2 comb [EPB][CSTR] (row-major), phase3 h1 [EPB][H1STR]
    __shared__ __align__(16) unsigned short smem[EPB * H1STR];
    __shared__ float out_lds[EPB];

    int tid = threadIdx.x;
    int wave = tid >> 6, lane = tid & 63;
    int lm = lane & 15, quad = lane >> 4;
    int e32 = lane & 31, hi = lane >> 5;
    int e0 = blockIdx.x * EPB;

    if (tid < EPB) out_lds[tid] = 0.f;

    // ---- Phase 1a (issue): gather loads of node_f[src], node_f[dst] into regs ----
    int gi = tid >> 3, gp = tid & 7;
    uint4 gs0, gs1, gd0, gd1;
    {
        int e = e0 + gi;
        int ec = e < N_EDGES ? e : N_EDGES - 1;
        int s = edge_index[ec];
        int d = edge_index[N_EDGES + ec];
        const uint4* ps = (const uint4*)(node_f + s * HID + gp * 16);
        const uint4* pd = (const uint4*)(node_f + d * HID + gp * 16);
        gs0 = ps[0]; gs1 = ps[1];
        gd0 = pd[0]; gd1 = pd[1];
    }

    // ---- Phase 1b: edge_f^T = We^T @ edge_attr^T (16x16x32), cols [256,384) ----
    {
        int nt = wave & 3;
        int mbase = (wave >> 2) * 4;
        int erow = e0 + nt * 16 + lm;
        if (erow >= N_EDGES) erow = N_EDGES - 1;

        f4v zero4 = {0.f, 0.f, 0.f, 0.f};
        f4v acc[4];
        #pragma unroll
        for (int t = 0; t < 4; ++t) acc[t] = zero4;

        for (int kb = 0; kb < 2; ++kb) {
            s8v b = load_a_f32(edge_attr, erow, EDGE_IN, kb * 32 + quad * 8);
            #pragma unroll
            for (int t = 0; t < 4; ++t) {
                s8v a = *(const s8v*)(Wep + (((kb * 8 + mbase + t) * 64 + lane) << 3));
                acc[t] = __builtin_amdgcn_mfma_f32_16x16x32_bf16(a, b, acc[t], 0, 0, 0);
            }
        }
        {
            uint4* cs = (uint4*)(smem + gi * CSTR + gp * 16);
            uint4* cd = (uint4*)(smem + gi * CSTR + 128 + gp * 16);
            cs[0] = gs0; cs[1] = gs1;
            cd[0] = gd0; cd[1] = gd1;
        }
        int edge = nt * 16 + lm;
        #pragma unroll
        for (int t = 0; t < 4; ++t) {
            int col = (mbase + t) * 16 + quad * 4;
            float4 bv = *(const float4*)(be + col);
            uint2 pk;
            pk.x = pk_bf16(fmaxf(acc[t][0] + bv.x, 0.f), fmaxf(acc[t][1] + bv.y, 0.f));
            pk.y = pk_bf16(fmaxf(acc[t][2] + bv.z, 0.f), fmaxf(acc[t][3] + bv.w, 0.f));
            *(uint2*)(smem + edge * CSTR + 256 + col) = pk;
        }
    }

    // Phase-2 weight prologue: issue A(ks=0) BEFORE the barrier (barrier's
    // vmcnt(0) drain covers its latency and zeroes the counter).
    // W1p 32-pack: mt stride 512 shorts, ks stride 16*512=8192 shorts.
    const unsigned short* wb1 = W1p + (((wave * 2) * 64 + lane) << 3);
    s8v aev[2], aod[2];
    aev[0] = *(const s8v*)(wb1);
    aev[1] = *(const s8v*)(wb1 + 512);

    __syncthreads();

    // ---- Phase 2: h1^T = W1^T @ comb^T (32x32x16) ----
    // wave owns m-tiles {wave*2, wave*2+1} (32-wide), edge-tiles {0,1} (32-wide).
    // Full even/odd dbuf of A (global) and B (LDS); per step:
    //   issue A(ks+1) [2 vmem] + B(ks+1) [2 ds] -> s_waitcnt vmcnt(2) lgkmcnt(2)
    //   (retires the buffers issued one step earlier) -> 4 MFMA.
    f16v acc1[2][2];
    #pragma unroll
    for (int t = 0; t < 2; ++t)
        #pragma unroll
        for (int n = 0; n < 2; ++n)
            acc1[t][n] = (f16v){0.f,0.f,0.f,0.f,0.f,0.f,0.f,0.f,
                                0.f,0.f,0.f,0.f,0.f,0.f,0.f,0.f};

    {
        const unsigned short* brp = smem + e32 * CSTR + hi * 8;   // B base (k=0)
        s8v bev[2], bod[2];
        bev[0] = *(const s8v*)(brp);
        bev[1] = *(const s8v*)(brp + 32 * CSTR);

        const unsigned short* wnx = wb1 + 8192;   // A(ks+1)
        const unsigned short* bnx = brp + 16;     // B(ks+1)

        #pragma unroll 1
        for (int ks = 0; ks < 24; ks += 2) {
            // even: consume (aev,bev)(ks), prefetch (aod,bod)(ks+1)
            aod[0] = *(const s8v*)(wnx);
            aod[1] = *(const s8v*)(wnx + 512);
            wnx += 8192;
            bod[0] = *(const s8v*)(bnx);
            bod[1] = *(const s8v*)(bnx + 32 * CSTR);
            bnx += 16;
            asm volatile("s_waitcnt vmcnt(2) lgkmcnt(2)" ::: "memory");
            __builtin_amdgcn_sched_barrier(0);
            #pragma unroll
            for (int t = 0; t < 2; ++t)
                #pragma unroll
                for (int n = 0; n < 2; ++n)
                    acc1[t][n] = __builtin_amdgcn_mfma_f32_32x32x16_bf16(aev[t], bev[n], acc1[t][n], 0, 0, 0);
            // odd: consume (aod,bod)(ks+1), prefetch (aev,bev)(ks+2)
            // (last odd step prefetches A(24) -> lands in W2p (adjacent, unused);
            //  B(24) reads the row pad / next row — in-bounds LDS junk, unused)
            aev[0] = *(const s8v*)(wnx);
            aev[1] = *(const s8v*)(wnx + 512);
            wnx += 8192;
            bev[0] = *(const s8v*)(bnx);
            bev[1] = *(const s8v*)(bnx + 32 * CSTR);
            bnx += 16;
            asm volatile("s_waitcnt vmcnt(2) lgkmcnt(2)" ::: "memory");
            __builtin_amdgcn_sched_barrier(0);
            #pragma unroll
            for (int t = 0; t < 2; ++t)
                #pragma unroll
                for (int n = 0; n < 2; ++n)
                    acc1[t][n] = __builtin_amdgcn_mfma_f32_32x32x16_bf16(aod[t], bod[n], acc1[t][n], 0, 0, 0);
        }
    }
    __syncthreads();  // everyone done reading comb before h1 overwrites it
                      // (also drains the junk A(24) prefetch)

    // h1 = relu(acc1 + b1) -> smem[edge][m], bf16. C map: col(edge)=l&31,
    // row(m offset) = (r&3) + 8*(r>>2) + 4*hi.
    {
        #pragma unroll
        for (int t = 0; t < 2; ++t) {
            int mb = (wave * 2 + t) * 32 + 4 * hi;
            #pragma unroll
            for (int g = 0; g < 4; ++g) {
                float4 bv = *(const float4*)(b1 + mb + g * 8);
                #pragma unroll
                for (int n = 0; n < 2; ++n) {
                    int edge = n * 32 + e32;
                    uint2 pk;
                    pk.x = pk_bf16(fmaxf(acc1[t][n][4 * g + 0] + bv.x, 0.f),
                                   fmaxf(acc1[t][n][4 * g + 1] + bv.y, 0.f));
                    pk.y = pk_bf16(fmaxf(acc1[t][n][4 * g + 2] + bv.z, 0.f),
                                   fmaxf(acc1[t][n][4 * g + 3] + bv.w, 0.f));
                    *(uint2*)(smem + edge * H1STR + mb + g * 8) = pk;
                }
            }
        }
    }

    // Phase-3 weight prologue before the publish barrier.
    // W2p 32-pack: mt stride 512 shorts, ks stride 8*512=4096 shorts.
    const unsigned short* wb2 = W2p + ((wave * 64 + lane) << 3);
    s8v a3ev, a3od;
    a3ev = *(const s8v*)(wb2);

    __syncthreads();

    // ---- Phase 3: h2^T = W2^T @ h1^T (32x32x16) ----
    // wave owns m-tile {wave}, edge-tiles {0,1}. K=512 -> 32 steps of 16.
    f16v acc2[2];
    #pragma unroll
    for (int n = 0; n < 2; ++n)
        acc2[n] = (f16v){0.f,0.f,0.f,0.f,0.f,0.f,0.f,0.f,
                         0.f,0.f,0.f,0.f,0.f,0.f,0.f,0.f};

    {
        const unsigned short* hrp = smem + e32 * H1STR + hi * 8;
        s8v bev[2], bod[2];
        bev[0] = *(const s8v*)(hrp);
        bev[1] = *(const s8v*)(hrp + 32 * H1STR);

        const unsigned short* wnx = wb2 + 4096;
        const unsigned short* bnx = hrp + 16;

        #pragma unroll 1
        for (int ks = 0; ks < 32; ks += 2) {
            // even: consume ev(ks), prefetch od(ks+1)
            a3od = *(const s8v*)(wnx);
            wnx += 4096;
            bod[0] = *(const s8v*)(bnx);
            bod[1] = *(const s8v*)(bnx + 32 * H1STR);
            bnx += 16;
            asm volatile("s_waitcnt vmcnt(1) lgkmcnt(2)" ::: "memory");
            __builtin_amdgcn_sched_barrier(0);
            #pragma unroll
            for (int n = 0; n < 2; ++n)
                acc2[n] = __builtin_amdgcn_mfma_f32_32x32x16_bf16(a3ev, bev[n], acc2[n], 0, 0, 0);
            // odd: consume od(ks+1), prefetch ev(ks+2)
            // (last odd prefetches A(32) -> lands in Wnp (adjacent, unused);
            //  B(32) reads pad/out_lds region — in-LDS junk, unused)
            a3ev = *(const s8v*)(wnx);
            wnx += 4096;
            bev[0] = *(const s8v*)(bnx);
            bev[1] = *(const s8v*)(bnx + 32 * H1STR);
            bnx += 16;
            asm volatile("s_waitcnt vmcnt(1) lgkmcnt(2)" ::: "memory");
            __builtin_amdgcn_sched_barrier(0);
            #pragma unroll
            for (int n = 0; n < 2; ++n)
                acc2[n] = __builtin_amdgcn_mfma_f32_32x32x16_bf16(a3od, bod[n], acc2[n], 0, 0, 0);
        }
    }

    // ---- Epilogue: relu(h2+b2) . W3 — per-lane partial over 16 m, 2-lane reduce ----
    {
        int mb = wave * 32 + 4 * hi;
        float p0 = 0.f, p1 = 0.f;
        #pragma unroll
        for (int g = 0; g < 4; ++g) {
            float4 bv = *(const float4*)(b2 + mb + g * 8);
            float4 wv = *(const float4*)(W3 + mb + g * 8);
            p0 += fmaxf(acc2[0][4 * g + 0] + bv.x, 0.f) * wv.x;
            p0 += fmaxf(acc2[0][4 * g + 1] + bv.y, 0.f) * wv.y;
            p0 += fmaxf(acc2[0][4 * g + 2] + bv.z, 0.f) * wv.z;
            p0 += fmaxf(acc2[0][4 * g + 3] + bv.w, 0.f) * wv.w;
            p1 += fmaxf(acc2[1][4 * g + 0] + bv.x, 0.f) * wv.x;
            p1 += fmaxf(acc2[1][4 * g + 1] + bv.y, 0.f) * wv.y;
            p1 += fmaxf(acc2[1][4 * g + 2] + bv.z, 0.f) * wv.z;
            p1 += fmaxf(acc2[1][4 * g + 3] + bv.w, 0.f) * wv.w;
        }
        p0 += __shfl_xor(p0, 32);
        p1 += __shfl_xor(p1, 32);
        if (hi == 0) {
            atomicAdd(&out_lds[e32], p0);
            atomicAdd(&out_lds[32 + e32], p1);
        }
    }
    __syncthreads();

    if (tid < EPB) {
        int e = e0 + tid;
        if (e < N_EDGES) out[e] = out_lds[tid] + b3[0];
    }
}

extern "C" void kernel_launch(void* const* d_in, const int* in_sizes, int n_in,
                              void* d_out, int out_size, void* d_ws, size_t ws_size,
                              hipStream_t stream)
{
    const float* x          = (const float*)d_in[0];
    const int*   edge_index = (const int*)d_in[1];
    const float* edge_attr  = (const float*)d_in[2];
    const float* Wn = (const float*)d_in[3];
    const float* bn = (const float*)d_in[4];
    const float* We = (const float*)d_in[5];
    const float* be = (const float*)d_in[6];
    const float* W1 = (const float*)d_in[7];
    const float* b1 = (const float*)d_in[8];
    const float* W2 = (const float*)d_in[9];
    const float* b2 = (const float*)d_in[10];
    const float* W3 = (const float*)d_in[11];
    const float* b3 = (const float*)d_in[12];
    float* out = (float*)d_out;

    // Workspace layout (order matters: W2p directly follows W1p so phase-2's
    // guard-free A(24) prefetch lands in W2p; Wnp follows W2p for phase-3's
    // A(32) prefetch).
    char* ws = (char*)d_ws;
    unsigned short* node_f = (unsigned short*)ws;                    // 12,800,000 B
    unsigned short* W1p = (unsigned short*)(ws + 12800000);          // 393,216 B
    unsigned short* W2p = (unsigned short*)(ws + 13193216);          // 262,144 B
    unsigned short* Wnp = (unsigned short*)(ws + 13455360);          // 32,768 B
    unsigned short* Wep = (unsigned short*)(ws + 13488128);          // 16,384 B

    pack_all<<<(PACK_TOTAL + 255) / 256, 256, 0, stream>>>(Wn, We, W1, W2, Wnp, Wep, W1p, W2p);

    node_feat_kernel<<<(N_NODES + 63) / 64, 256, 0, stream>>>(x, Wnp, bn, node_f);

    fused_edge_kernel<<<(N_EDGES + EPB - 1) / EPB, 512, 0, stream>>>(
        edge_index, edge_attr, node_f, Wep, be, W1p, b1, W2p, b2, W3, b3, out);
}